// Round 9
// baseline (129.387 us; speedup 1.0000x reference)
//
#include <hip/hip_runtime.h>
#include <math.h>

#define NPTS 8192
#define GD 12
#define NCPAD 2048                 // padded cell count (2^11)
#define CELL_H (0.3f/(float)GD)    // 0.025 > 0.02 alignment radius
#define INV_H ((float)GD/0.3f)     // 40.0
#define ALIGN_T 4.0e-4f            // 0.02^2
#define K9 9
#define NWAVES 2048                // query waves: 4 rows each

// ws layout (bytes)
#define WS_POS    0                // float4[NPTS] sorted (x,y,z,|p|^2)
#define WS_ROT    131072           // float4[NPTS] sorted rotations
#define WS_CSTART 262144           // int[NCPAD+1]
#define WS_IDX    270352           // int[NPTS] sorted -> original
#define WS_CNTR   303120           // uint completion counter
#define WS_PART   303152           // float4[NWAVES] (32 KB)
#define WS_GCNT   335952           // int[NCPAD]
#define WS_AUX    344144           // int[NPTS] packed (cell | slot<<11)

// ---------------- build stage 1: count ----------------
__global__ __launch_bounds__(256) void gsr_count(
    const float* __restrict__ pos, unsigned char* __restrict__ ws)
{
    int* gcnt = (int*)(ws + WS_GCNT);
    int* aux  = (int*)(ws + WS_AUX);
    int p = blockIdx.x*256 + threadIdx.x;
    float x = pos[3*p], y = pos[3*p+1], z = pos[3*p+2];
    int ix = min((int)(x*INV_H), GD-1);
    int iy = min((int)(y*INV_H), GD-1);
    int iz = min((int)(z*INV_H), GD-1);
    int c = (ix*GD+iy)*GD+iz;
    int slot = atomicAdd(&gcnt[c], 1);
    aux[p] = c | (slot << 11);
}

// ---------------- build stage 2: scan (1 block, 2 cells/thread) ----------------
__global__ __launch_bounds__(1024) void gsr_scan(unsigned char* __restrict__ ws)
{
    const int* gcnt = (const int*)(ws + WS_GCNT);
    int* cellStart  = (int*)(ws + WS_CSTART);
    unsigned int* counter = (unsigned int*)(ws + WS_CNTR);
    __shared__ int sb[1024];
    int t = threadIdx.x;
    int c0 = gcnt[2*t], c1 = gcnt[2*t+1];
    sb[t] = c0 + c1;
    __syncthreads();
    for (int off = 1; off < 1024; off <<= 1) {
        int v = (t >= off) ? sb[t-off] : 0;
        __syncthreads();
        sb[t] += v;
        __syncthreads();
    }
    int incl = sb[t];
    int excl = incl - c0 - c1;
    cellStart[2*t]   = excl;
    cellStart[2*t+1] = excl + c0;
    if (t == 1023) cellStart[2048] = incl;
    if (t == 0) *counter = 0u;
}

// ---------------- build stage 3: scatter ----------------
__global__ __launch_bounds__(256) void gsr_scatter(
    const float* __restrict__ pos, const float* __restrict__ rot,
    unsigned char* __restrict__ ws)
{
    float4* sPos = (float4*)(ws + WS_POS);
    float4* sRot = (float4*)(ws + WS_ROT);
    const int* cellStart = (const int*)(ws + WS_CSTART);
    int* sIdx = (int*)(ws + WS_IDX);
    const int* aux = (const int*)(ws + WS_AUX);
    int p = blockIdx.x*256 + threadIdx.x;
    int a = aux[p];
    int c = a & (NCPAD-1);
    int dst = cellStart[c] + (a >> 11);
    float x = pos[3*p], y = pos[3*p+1], z = pos[3*p+2];
    // identical fmaf shape as query dot product -> self d2 == 0 exactly
    float w = fmaf(x, x, fmaf(y, y, z*z));
    sPos[dst] = make_float4(x, y, z, w);
    sRot[dst] = *(const float4*)(rot + 4*p);
    sIdx[dst] = p;
}

__device__ __forceinline__ void insert9(float (&d)[K9], float v) {
#pragma unroll
    for (int k = 0; k < K9; k++) { float lo = fminf(d[k], v); v = fmaxf(d[k], v); d[k] = lo; }
}

// serial extract-min wave merge (ONLY in the ultra-rare r>=3 shell path)
__device__ __forceinline__ void wave_merge9x(const float (&dd)[K9], float& s8, float& d9) {
    float t0=dd[0],t1=dd[1],t2=dd[2],t3=dd[3],t4=dd[4],t5=dd[5],t6=dd[6],t7=dd[7],t8=dd[8];
    float ssum = 0.f, m = 0.f;
#pragma unroll
    for (int k = 0; k < 9; k++) {
        m = t0;
#pragma unroll
        for (int o = 32; o > 0; o >>= 1) m = fminf(m, __shfl_xor(m, o, 64));
        bool take = (t0 == m);
        t0=take?t1:t0; t1=take?t2:t1; t2=take?t3:t2; t3=take?t4:t3;
        t4=take?t5:t4; t5=take?t6:t5; t6=take?t7:t6; t7=take?t8:t7;
        t8=take?1e30f:t8;
        if (k >= 1) ssum += sqrtf(fmaxf(m, 0.f) + 1e-12f);
    }
    s8 = ssum; d9 = m;
}

// ---------------- query: 4 rows/wave, 16 lanes/row, in-kernel fallback ----------------
__global__ __launch_bounds__(64) void gsr_qknn(
    const float* __restrict__ scl,
    const float* __restrict__ opa,
    unsigned char* __restrict__ ws,
    float* __restrict__ out)
{
    const float4* sPos = (const float4*)(ws + WS_POS);
    const float4* sRot = (const float4*)(ws + WS_ROT);
    const int* cellStart = (const int*)(ws + WS_CSTART);
    const int* sIdx = (const int*)(ws + WS_IDX);
    unsigned int* counter = (unsigned int*)(ws + WS_CNTR);
    float* partials = (float*)(ws + WS_PART);

    const int lane = threadIdx.x;          // 0..63 (single wave)
    const int sub  = lane & 15;            // lane within row-group
    const int w    = blockIdx.x;           // wave id
    const int s    = (w << 2) + (lane >> 4);  // this lane's row

    const float4 Pv = sPos[s];
    const float4 Q  = sRot[s];
    const float Px = Pv.x, Py = Pv.y, Pz = Pv.z, Pw = Pv.w;
    const int cx = min((int)(Px*INV_H), GD-1);
    const int cy = min((int)(Py*INV_H), GD-1);
    const int cz = min((int)(Pz*INV_H), GD-1);
    const int zlo = max(cz-1, 0), zhi = min(cz+1, GD-1);

    // 9 column ranges of the row's ring-1 box, flattened prefix
    int rsv[9], O[10];
    O[0] = 0;
#pragma unroll
    for (int c9 = 0; c9 < 9; c9++) {
        int jx = cx + c9/3 - 1, jy = cy + c9%3 - 1;
        bool v = (jx >= 0) & (jx < GD) & (jy >= 0) & (jy < GD);
        int b = v ? ((jx*GD + jy)*GD) : 0;
        int lo = cellStart[b + zlo];
        int hi = cellStart[b + zhi + 1];
        rsv[c9] = lo;
        O[c9+1] = O[c9] + (v ? (hi - lo) : 0);
    }
    const int T = O[9];

    float d[K9];
#pragma unroll
    for (int k = 0; k < K9; k++) d[k] = 1e30f;
    float asum = 0.f, acnt = 0.f;

    // coalesced flattened scan: 16 contiguous lanes march the row's candidates
    for (int g = sub; g < T; g += 16) {
        int o = 0;
#pragma unroll
        for (int i = 0; i < 9; i++) {
            bool in = (g >= O[i]) & (g < O[i+1]);
            o = in ? (rsv[i] + (g - O[i])) : o;
        }
        float4 p = sPos[o];
        float4 rt = sRot[o];
        float dt = fmaf(Px, p.x, fmaf(Py, p.y, Pz*p.z));
        float c = fmaf(-2.f, dt, Pw + p.w);       // d^2, self == 0 exact
        insert9(d, c);
        bool a = (c < ALIGN_T) & (o != s);
        float dq = fmaf(Q.x, rt.x, fmaf(Q.y, rt.y, fmaf(Q.z, rt.z, Q.w*rt.w)));
        asum += a ? (1.f - fabsf(dq)) : 0.f;
        acnt += a ? 1.f : 0.f;
    }

    // 4-stage butterfly merge within each 16-lane row-group (exact top-9)
#pragma unroll
    for (int off = 1; off < 16; off <<= 1) {
        float t[K9];
#pragma unroll
        for (int k = 0; k < K9; k++) t[k] = __shfl_xor(d[k], off, 64);
#pragma unroll
        for (int m = 0; m < K9; m++) insert9(d, t[m]);
    }

    float flat = 0.f, dens = 0.f;
    bool fail = false;
    if (sub == 0) {
        float s8 = 0.f;
#pragma unroll
        for (int k = 1; k < K9; k++) s8 += sqrtf(fmaxf(d[k], 0.f) + 1e-12f);
        float cov = 1e30f;
        if (cx-1 > 0)    cov = fminf(cov, Px - (float)(cx-1)*CELL_H);
        if (cx+1 < GD-1) cov = fminf(cov, (float)(cx+2)*CELL_H - Px);
        if (cy-1 > 0)    cov = fminf(cov, Py - (float)(cy-1)*CELL_H);
        if (cy+1 < GD-1) cov = fminf(cov, (float)(cy+2)*CELL_H - Py);
        if (cz-1 > 0)    cov = fminf(cov, Pz - (float)(cz-1)*CELL_H);
        if (cz+1 < GD-1) cov = fminf(cov, (float)(cz+2)*CELL_H - Pz);
        fail = !(d[8] <= cov*cov);
        int i = sIdx[s];
        float ea = expf(scl[3*i]), eb = expf(scl[3*i+1]), ec = expf(scl[3*i+2]);
        float mn = fminf(ea, fminf(eb, ec));
        float mx = fmaxf(ea, fmaxf(eb, ec));
        float md = fminf(fmaxf(ea, eb), fmaxf(fminf(ea, eb), ec));
        flat = logf(mx/(mn+1e-8f)+1e-8f) + 0.1f/(fabsf(mx-md)+0.001f);
        if (!fail) dens = fabsf(s8*0.125f - 0.01f) * opa[i];
    }

    // wave-cooperative exact fallback for coverage-failing rows (~18% of rows)
    unsigned long long fmask = __ballot(fail);
    while (fmask) {
        int fl = (int)__ffsll((long long)fmask) - 1;
        fmask &= fmask - 1;
        float FPx = __shfl(Px, fl, 64), FPy = __shfl(Py, fl, 64);
        float FPz = __shfl(Pz, fl, 64), FPw = __shfl(Pw, fl, 64);
        int fcx = __shfl(cx, fl, 64), fcy = __shfl(cy, fl, 64), fcz = __shfl(cz, fl, 64);
        int srow = (w << 2) + (fl >> 4);

        float e[K9];
#pragma unroll
        for (int k = 0; k < K9; k++) e[k] = 1e30f;

        // full 5x5x5 box, all 64 lanes coalesced
        {
            int zl = max(fcz-2, 0), zh = min(fcz+2, GD-1);
            for (int jx = max(fcx-2,0); jx <= min(fcx+2,GD-1); jx++) {
                for (int jy = max(fcy-2,0); jy <= min(fcy+2,GD-1); jy++) {
                    int b = (jx*GD+jy)*GD;
                    int rs = cellStart[b+zl], re = cellStart[b+zh+1];
                    for (int o = rs + lane; o < re; o += 64) {
                        float4 p = sPos[o];
                        float dt = fmaf(FPx, p.x, fmaf(FPy, p.y, FPz*p.z));
                        float c = fmaf(-2.f, dt, FPw + p.w);
                        insert9(e, c);
                    }
                }
            }
        }
        // 6-stage full-wave butterfly -> all lanes hold row top-9
#pragma unroll
        for (int off = 1; off < 64; off <<= 1) {
            float t[K9];
#pragma unroll
            for (int k = 0; k < K9; k++) t[k] = __shfl_xor(e[k], off, 64);
#pragma unroll
            for (int m = 0; m < K9; m++) insert9(e, t[m]);
        }
        float f8 = 0.f;
#pragma unroll
        for (int k = 1; k < K9; k++) f8 += sqrtf(fmaxf(e[k], 0.f) + 1e-12f);
        float fd9 = e[8];
        float cv2 = 1e30f;
        if (fcx-2 > 0)    cv2 = fminf(cv2, FPx - (float)(fcx-2)*CELL_H);
        if (fcx+2 < GD-1) cv2 = fminf(cv2, (float)(fcx+3)*CELL_H - FPx);
        if (fcy-2 > 0)    cv2 = fminf(cv2, FPy - (float)(fcy-2)*CELL_H);
        if (fcy+2 < GD-1) cv2 = fminf(cv2, (float)(fcy+3)*CELL_H - FPy);
        if (fcz-2 > 0)    cv2 = fminf(cv2, FPz - (float)(fcz-2)*CELL_H);
        if (fcz+2 < GD-1) cv2 = fminf(cv2, (float)(fcz+3)*CELL_H - FPz);
        if (!(fd9 <= cv2*cv2)) {
            // expanding Chebyshev shells r>=3 (provably exact, ~never runs)
            for (int r = 3; r <= GD; r++) {
                int xlo = max(fcx-r,0), xhi = min(fcx+r,GD-1);
                int ylo = max(fcy-r,0), yhi = min(fcy+r,GD-1);
                for (int jx = xlo; jx <= xhi; jx++) {
                    int adx = (jx>fcx)?(jx-fcx):(fcx-jx);
                    for (int jy = ylo; jy <= yhi; jy++) {
                        int ady = (jy>fcy)?(jy-fcy):(fcy-jy);
                        int b = (jx*GD+jy)*GD;
                        int rs0=0,re0=0, rs1=0,re1=0;
                        if (adx==r || ady==r) {
                            rs0 = cellStart[b+max(fcz-r,0)];
                            re0 = cellStart[b+min(fcz+r,GD-1)+1];
                        } else {
                            if (fcz-r >= 0)    { rs0=cellStart[b+fcz-r]; re0=cellStart[b+fcz-r+1]; }
                            if (fcz+r <= GD-1) { rs1=cellStart[b+fcz+r]; re1=cellStart[b+fcz+r+1]; }
                        }
#pragma unroll
                        for (int pass = 0; pass < 2; pass++) {
                            int rs = pass? rs1: rs0, re = pass? re1: re0;
                            for (int o = rs + lane; o < re; o += 64) {
                                float4 p = sPos[o];
                                float dt = fmaf(FPx, p.x, fmaf(FPy, p.y, FPz*p.z));
                                float c = fmaf(-2.f, dt, FPw + p.w);
                                insert9(e, c);
                            }
                        }
                    }
                }
                wave_merge9x(e, f8, fd9);
                float cv = 1e30f;
                if (fcx-r > 0)    cv = fminf(cv, FPx - (float)(fcx-r)*CELL_H);
                if (fcx+r < GD-1) cv = fminf(cv, (float)(fcx+r+1)*CELL_H - FPx);
                if (fcy-r > 0)    cv = fminf(cv, FPy - (float)(fcy-r)*CELL_H);
                if (fcy+r < GD-1) cv = fminf(cv, (float)(fcy+r+1)*CELL_H - FPy);
                if (fcz-r > 0)    cv = fminf(cv, FPz - (float)(fcz-r)*CELL_H);
                if (fcz+r < GD-1) cv = fminf(cv, (float)(fcz+r+1)*CELL_H - FPz);
                if (fd9 <= cv*cv) break;
            }
        }
        if (lane == fl) dens = fabsf(f8*0.125f - 0.01f) * opa[sIdx[srow]];
    }

    // wave reduce 4 scalars -> per-wave partial -> last-finisher combine
    float vals[4] = {asum, acnt, flat, dens};
#pragma unroll
    for (int qi = 0; qi < 4; qi++) {
        float v = vals[qi];
        for (int o = 32; o > 0; o >>= 1) v += __shfl_down(v, o, 64);
        vals[qi] = v;
    }
    unsigned int old = 0;
    if (lane == 0) {
        *(float4*)(partials + w*4) = make_float4(vals[0], vals[1], vals[2], vals[3]);
        __threadfence();
        old = atomicAdd(counter, 1u);
    }
    old = __shfl(old, 0, 64);
    if (old == NWAVES - 1) {
        __threadfence();
        float t0=0.f, t1=0.f, t2=0.f, t3=0.f;
        for (int b = lane; b < NWAVES; b += 64) {
            float4 pv = *(const float4*)(partials + b*4);
            t0 += pv.x; t1 += pv.y; t2 += pv.z; t3 += pv.w;
        }
#pragma unroll
        for (int o = 32; o > 0; o >>= 1) {
            t0 += __shfl_down(t0, o, 64); t1 += __shfl_down(t1, o, 64);
            t2 += __shfl_down(t2, o, 64); t3 += __shfl_down(t3, o, 64);
        }
        if (lane == 0) {
            float flat_loss = -t2 / (float)NPTS;
            float align_loss = (t1 > 0.f) ? (t0/t1) : 0.f;
            float dens_loss = t3 / (float)NPTS;
            out[0] = 1.0f*flat_loss + 0.5f*align_loss + 0.2f*dens_loss;
        }
    }
}

extern "C" void kernel_launch(void* const* d_in, const int* in_sizes, int n_in,
                              void* d_out, int out_size, void* d_ws, size_t ws_size,
                              hipStream_t stream) {
    const float* pos = (const float*)d_in[0];
    const float* rot = (const float*)d_in[1];
    const float* scl = (const float*)d_in[2];
    const float* opa = (const float*)d_in[3];
    unsigned char* ws = (unsigned char*)d_ws;

    hipMemsetAsync(ws + WS_GCNT, 0, NCPAD*sizeof(int), stream);
    gsr_count  <<<NPTS/256, 256, 0, stream>>>(pos, ws);
    gsr_scan   <<<1, 1024, 0, stream>>>(ws);
    gsr_scatter<<<NPTS/256, 256, 0, stream>>>(pos, rot, ws);
    gsr_qknn   <<<NWAVES, 64, 0, stream>>>(scl, opa, ws, (float*)d_out);
}

// Round 10
// 92.690 us; speedup vs baseline: 1.3959x; 1.3959x over previous
//
#include <hip/hip_runtime.h>
#include <math.h>

#define NPTS 8192
#define GD 8
#define NCELL 512                  // GD^3
#define CELL_H (0.3f/(float)GD)    // 0.0375 > 0.02 alignment radius
#define INV_H ((float)GD/0.3f)
#define ALIGN_T 4.0e-4f            // 0.02^2
#define K5 5
#define K9 9
#define CAP 768                    // LDS point capacity (box ~430, Poisson tail << 768)

// ws layout (bytes)
#define WS_POS    0                // float4[NPTS] sorted (x,y,z,|p|^2)
#define WS_ROT    131072           // float4[NPTS] sorted rotations
#define WS_CSTART 262144           // int[NCELL+1]
#define WS_IDX    266240           // int[NPTS] sorted -> original
#define WS_CNTR   299008           // uint completion counter
#define WS_PART   299024           // float4[NCELL] per-block partials
#define WS_GCNT   307216           // int[NCELL]
#define WS_AUX    309264           // int[NPTS] packed (cell | slot<<9)

// ---------------- build stage 1: count ----------------
__global__ __launch_bounds__(256) void gsr_count(
    const float* __restrict__ pos, unsigned char* __restrict__ ws)
{
    int* gcnt = (int*)(ws + WS_GCNT);
    int* aux  = (int*)(ws + WS_AUX);
    int p = blockIdx.x*256 + threadIdx.x;
    float x = pos[3*p], y = pos[3*p+1], z = pos[3*p+2];
    int ix = min((int)(x*INV_H), GD-1);
    int iy = min((int)(y*INV_H), GD-1);
    int iz = min((int)(z*INV_H), GD-1);
    int c = (ix*GD+iy)*GD+iz;
    int slot = atomicAdd(&gcnt[c], 1);
    aux[p] = c | (slot << 9);
}

// ---------------- build stage 2: scan (1 block, 512 thr) ----------------
__global__ __launch_bounds__(NCELL) void gsr_scan(unsigned char* __restrict__ ws)
{
    const int* gcnt = (const int*)(ws + WS_GCNT);
    int* cellStart  = (int*)(ws + WS_CSTART);
    unsigned int* counter = (unsigned int*)(ws + WS_CNTR);
    __shared__ int sb[NCELL];
    int t = threadIdx.x;
    int cn = gcnt[t];
    sb[t] = cn;
    __syncthreads();
    for (int off = 1; off < NCELL; off <<= 1) {
        int v = (t >= off) ? sb[t-off] : 0;
        __syncthreads();
        sb[t] += v;
        __syncthreads();
    }
    cellStart[t+1] = sb[t];
    if (t == 0) { cellStart[0] = 0; *counter = 0u; }
}

// ---------------- build stage 3: scatter ----------------
__global__ __launch_bounds__(256) void gsr_scatter(
    const float* __restrict__ pos, const float* __restrict__ rot,
    unsigned char* __restrict__ ws)
{
    float4* sPos = (float4*)(ws + WS_POS);
    float4* sRot = (float4*)(ws + WS_ROT);
    const int* cellStart = (const int*)(ws + WS_CSTART);
    int* sIdx = (int*)(ws + WS_IDX);
    const int* aux = (const int*)(ws + WS_AUX);
    int p = blockIdx.x*256 + threadIdx.x;
    int a = aux[p];
    int c = a & (NCELL-1);
    int dst = cellStart[c] + (a >> 9);
    float x = pos[3*p], y = pos[3*p+1], z = pos[3*p+2];
    // identical fmaf shape as query dot product -> self d2 == 0 exactly
    float w = fmaf(x, x, fmaf(y, y, z*z));
    sPos[dst] = make_float4(x, y, z, w);
    sRot[dst] = *(const float4*)(rot + 4*p);
    sIdx[dst] = p;
}

__device__ __forceinline__ void insert5(float (&d)[K5], float v) {
#pragma unroll
    for (int k = 0; k < K5; k++) { float lo = fminf(d[k], v); v = fmaxf(d[k], v); d[k] = lo; }
}
__device__ __forceinline__ void insert9(float (&d)[K9], float v) {
#pragma unroll
    for (int k = 0; k < K9; k++) { float lo = fminf(d[k], v); v = fmaxf(d[k], v); d[k] = lo; }
}

// dual interleaved extract-min over two K5 lists (2x ILP on the shuffle chain)
__device__ __forceinline__ void dual_merge5(const float (&dA)[K5], const float (&dB)[K5],
                                            float& s8A, float& d9A, float& s8B, float& d9B) {
    float a0=dA[0],a1=dA[1],a2=dA[2],a3=dA[3],a4=dA[4];
    float b0=dB[0],b1=dB[1],b2=dB[2],b3=dB[3],b4=dB[4];
    float sA=0.f, sB=0.f, mA=0.f, mB=0.f;
#pragma unroll
    for (int k = 0; k < 9; k++) {
        mA = a0; mB = b0;
#pragma unroll
        for (int o = 32; o > 0; o >>= 1) {
            mA = fminf(mA, __shfl_xor(mA, o, 64));
            mB = fminf(mB, __shfl_xor(mB, o, 64));
        }
        bool tA = (a0 == mA), tB = (b0 == mB);
        a0=tA?a1:a0; a1=tA?a2:a1; a2=tA?a3:a2; a3=tA?a4:a3; a4=tA?1e30f:a4;
        b0=tB?b1:b0; b1=tB?b2:b1; b2=tB?b3:b2; b3=tB?b4:b3; b4=tB?1e30f:b4;
        if (k >= 1) {
            sA += sqrtf(fmaxf(mA, 0.f) + 1e-12f);
            sB += sqrtf(fmaxf(mB, 0.f) + 1e-12f);
        }
    }
    s8A = sA; d9A = mA; s8B = sB; d9B = mB;
}

// serial extract-min over K9 (cold fallback only)
__device__ __forceinline__ void wave_merge9x(const float (&dd)[K9], float& s8, float& d9) {
    float t0=dd[0],t1=dd[1],t2=dd[2],t3=dd[3],t4=dd[4],t5=dd[5],t6=dd[6],t7=dd[7],t8=dd[8];
    float ssum = 0.f, m = 0.f;
#pragma unroll
    for (int k = 0; k < 9; k++) {
        m = t0;
#pragma unroll
        for (int o = 32; o > 0; o >>= 1) m = fminf(m, __shfl_xor(m, o, 64));
        bool take = (t0 == m);
        t0=take?t1:t0; t1=take?t2:t1; t2=take?t3:t2; t3=take?t4:t3;
        t4=take?t5:t4; t5=take?t6:t5; t6=take?t7:t6; t7=take?t8:t7;
        t8=take?1e30f:t8;
        if (k >= 1) ssum += sqrtf(fmaxf(m, 0.f) + 1e-12f);
    }
    s8 = ssum; d9 = m;
}

// ---------------- query: one block per cell, LDS-staged box ----------------
__global__ __launch_bounds__(512) void gsr_qcell(
    const float* __restrict__ scl,
    const float* __restrict__ opa,
    unsigned char* __restrict__ ws,
    float* __restrict__ out)
{
    const float4* sPos = (const float4*)(ws + WS_POS);
    const float4* sRot = (const float4*)(ws + WS_ROT);
    const int* cellStart = (const int*)(ws + WS_CSTART);
    const int* sIdx = (const int*)(ws + WS_IDX);
    unsigned int* counter = (unsigned int*)(ws + WS_CNTR);
    float* partials = (float*)(ws + WS_PART);

    __shared__ float4 lp[CAP];
    __shared__ float4 lr[CAP];
    __shared__ float red[8][4];
    __shared__ int lastflag;

    const int tid = threadIdx.x;
    const int lane = tid & 63;
    const int wv = tid >> 6;
    const int c = blockIdx.x;
    const int cx = c >> 6, cy = (c >> 3) & 7, cz = c & 7;
    const int zlo = max(cz-1, 0), zhi = min(cz+1, GD-1);
    const int rowStart = cellStart[c], rowEnd = cellStart[c+1];
    const int nrows = rowEnd - rowStart;

    // 9 column ranges of the cell's ring-1 box (uniform per block)
    int rsv[9], O[10];
    O[0] = 0;
#pragma unroll
    for (int c9 = 0; c9 < 9; c9++) {
        int jx = cx + c9/3 - 1, jy = cy + c9%3 - 1;
        bool v = (jx >= 0) & (jx < GD) & (jy >= 0) & (jy < GD);
        int b = v ? ((jx*GD + jy)*GD) : 0;
        int lo = cellStart[b + zlo];
        int hi = cellStart[b + zhi + 1];
        rsv[c9] = lo;
        O[c9+1] = O[c9] + (v ? (hi - lo) : 0);
    }
    const int nbox = O[9];
    const bool useLds = (nbox <= CAP);

    if (useLds) {
        for (int t = tid; t < nbox; t += 512) {
            int o = 0;
#pragma unroll
            for (int i = 0; i < 9; i++) {
                bool in = (t >= O[i]) & (t < O[i+1]);
                o = in ? (rsv[i] + (t - O[i])) : o;
            }
            lp[t] = sPos[o];
            lr[t] = sRot[o];
        }
    }
    __syncthreads();

    float asum = 0.f, acnt = 0.f, flatAcc = 0.f, densAcc = 0.f;

    const int npairs = (nrows + 1) >> 1;
    for (int pi = wv; pi < npairs; pi += 8) {
        const int r0 = rowStart + 2*pi;
        const int r1 = r0 + 1;
        const bool bval = (r1 < rowEnd);
        const float4 P0 = sPos[r0];
        const float4 P1 = bval ? sPos[r1] : P0;
        const float4 Q0 = sRot[r0];
        const float4 Q1 = bval ? sRot[r1] : Q0;

        float dA[K5], dB[K5];
#pragma unroll
        for (int k = 0; k < K5; k++) { dA[k] = 1e30f; dB[k] = 1e30f; }

        for (int g = lane; g < nbox; g += 64) {
            float4 p, rt;
            if (useLds) { p = lp[g]; rt = lr[g]; }
            else {
                int o = 0;
#pragma unroll
                for (int i = 0; i < 9; i++) {
                    bool in = (g >= O[i]) & (g < O[i+1]);
                    o = in ? (rsv[i] + (g - O[i])) : o;
                }
                p = sPos[o]; rt = sRot[o];
            }
            float dt0 = fmaf(P0.x, p.x, fmaf(P0.y, p.y, P0.z*p.z));
            float dt1 = fmaf(P1.x, p.x, fmaf(P1.y, p.y, P1.z*p.z));
            float cA = fmaf(-2.f, dt0, P0.w + p.w);   // d^2; self == 0.0f exactly
            float cB = fmaf(-2.f, dt1, P1.w + p.w);
            insert5(dA, cA);
            insert5(dB, cB);
            bool aA = (cA < ALIGN_T) & (cA != 0.0f);
            bool aB = (cB < ALIGN_T) & (cB != 0.0f) & bval;
            float dq0 = fmaf(Q0.x, rt.x, fmaf(Q0.y, rt.y, fmaf(Q0.z, rt.z, Q0.w*rt.w)));
            float dq1 = fmaf(Q1.x, rt.x, fmaf(Q1.y, rt.y, fmaf(Q1.z, rt.z, Q1.w*rt.w)));
            asum += aA ? (1.f - fabsf(dq0)) : 0.f;
            acnt += aA ? 1.f : 0.f;
            asum += aB ? (1.f - fabsf(dq1)) : 0.f;
            acnt += aB ? 1.f : 0.f;
        }

        float s8A, d9A, s8B, d9B;
        dual_merge5(dA, dB, s8A, d9A, s8B, d9B);

        // coverage of the ring-1 box, per row (wave-uniform branch)
#pragma unroll
        for (int rr = 0; rr < 2; rr++) {
            if (rr == 1 && !bval) break;
            const float Px = rr ? P1.x : P0.x;
            const float Py = rr ? P1.y : P0.y;
            const float Pz = rr ? P1.z : P0.z;
            const float Pw = rr ? P1.w : P0.w;
            float s8 = rr ? s8B : s8A;
            float d9 = rr ? d9B : d9A;
            float cov = 1e30f;
            if (cx-1 > 0)    cov = fminf(cov, Px - (float)(cx-1)*CELL_H);
            if (cx+1 < GD-1) cov = fminf(cov, (float)(cx+2)*CELL_H - Px);
            if (cy-1 > 0)    cov = fminf(cov, Py - (float)(cy-1)*CELL_H);
            if (cy+1 < GD-1) cov = fminf(cov, (float)(cy+2)*CELL_H - Py);
            if (cz-1 > 0)    cov = fminf(cov, Pz - (float)(cz-1)*CELL_H);
            if (cz+1 < GD-1) cov = fminf(cov, (float)(cz+2)*CELL_H - Pz);
            if (!(d9 <= cov*cov)) {
                // cold exact fallback: expanding boxes r>=2 from scratch (global reads)
                float e[K9];
#pragma unroll
                for (int k = 0; k < K9; k++) e[k] = 1e30f;
                for (int r = 2; r <= GD; r++) {
                    // full (2r+1)^3 clipped box rescanned (simple, ~never runs)
#pragma unroll
                    for (int k = 0; k < K9; k++) e[k] = 1e30f;
                    int zl = max(cz-r, 0), zh = min(cz+r, GD-1);
                    for (int jx = max(cx-r,0); jx <= min(cx+r,GD-1); jx++) {
                        for (int jy = max(cy-r,0); jy <= min(cy+r,GD-1); jy++) {
                            int b = (jx*GD+jy)*GD;
                            int rs = cellStart[b+zl], re = cellStart[b+zh+1];
                            for (int o = rs + lane; o < re; o += 64) {
                                float4 p = sPos[o];
                                float dt = fmaf(Px, p.x, fmaf(Py, p.y, Pz*p.z));
                                float cc = fmaf(-2.f, dt, Pw + p.w);
                                insert9(e, cc);
                            }
                        }
                    }
                    wave_merge9x(e, s8, d9);
                    float cv = 1e30f;
                    if (cx-r > 0)    cv = fminf(cv, Px - (float)(cx-r)*CELL_H);
                    if (cx+r < GD-1) cv = fminf(cv, (float)(cx+r+1)*CELL_H - Px);
                    if (cy-r > 0)    cv = fminf(cv, Py - (float)(cy-r)*CELL_H);
                    if (cy+r < GD-1) cv = fminf(cv, (float)(cy+r+1)*CELL_H - Py);
                    if (cz-r > 0)    cv = fminf(cv, Pz - (float)(cz-r)*CELL_H);
                    if (cz+r < GD-1) cv = fminf(cv, (float)(cz+r+1)*CELL_H - Pz);
                    if (d9 <= cv*cv) break;
                }
            }
            if (lane == 0) {
                int srow = rr ? r1 : r0;
                int i = sIdx[srow];
                densAcc += fabsf(s8*0.125f - 0.01f) * opa[i];
                float ea = expf(scl[3*i]), eb = expf(scl[3*i+1]), ec = expf(scl[3*i+2]);
                float mn = fminf(ea, fminf(eb, ec));
                float mx = fmaxf(ea, fmaxf(eb, ec));
                float md = fminf(fmaxf(ea, eb), fmaxf(fminf(ea, eb), ec));
                flatAcc += logf(mx/(mn+1e-8f)+1e-8f) + 0.1f/(fabsf(mx-md)+0.001f);
            }
        }
    }

    // block reduction
    float vals[4] = {asum, acnt, flatAcc, densAcc};
#pragma unroll
    for (int qi = 0; qi < 4; qi++) {
        float v = vals[qi];
        for (int o = 32; o > 0; o >>= 1) v += __shfl_down(v, o, 64);
        if (lane == 0) red[wv][qi] = v;
    }
    __syncthreads();
    if (tid == 0) {
        float t0=0,t1=0,t2=0,t3=0;
        for (int w = 0; w < 8; w++) { t0+=red[w][0]; t1+=red[w][1]; t2+=red[w][2]; t3+=red[w][3]; }
        *(float4*)(partials + blockIdx.x*4) = make_float4(t0,t1,t2,t3);
        __threadfence();
        unsigned int old = atomicAdd(counter, 1u);
        lastflag = (old == NCELL-1) ? 1 : 0;
    }
    __syncthreads();
    if (lastflag && wv == 0) {
        __threadfence();
        float t0=0,t1=0,t2=0,t3=0;
        for (int b = lane; b < NCELL; b += 64) {
            float4 pv = *(const float4*)(partials + b*4);
            t0+=pv.x; t1+=pv.y; t2+=pv.z; t3+=pv.w;
        }
#pragma unroll
        for (int o = 32; o > 0; o >>= 1) {
            t0+=__shfl_down(t0,o,64); t1+=__shfl_down(t1,o,64);
            t2+=__shfl_down(t2,o,64); t3+=__shfl_down(t3,o,64);
        }
        if (lane == 0) {
            float flat_loss = -t2 / (float)NPTS;
            float align_loss = (t1 > 0.f) ? (t0/t1) : 0.f;
            float dens_loss = t3 / (float)NPTS;
            out[0] = 1.0f*flat_loss + 0.5f*align_loss + 0.2f*dens_loss;
        }
    }
}

extern "C" void kernel_launch(void* const* d_in, const int* in_sizes, int n_in,
                              void* d_out, int out_size, void* d_ws, size_t ws_size,
                              hipStream_t stream) {
    const float* pos = (const float*)d_in[0];
    const float* rot = (const float*)d_in[1];
    const float* scl = (const float*)d_in[2];
    const float* opa = (const float*)d_in[3];
    unsigned char* ws = (unsigned char*)d_ws;

    hipMemsetAsync(ws + WS_GCNT, 0, NCELL*sizeof(int), stream);
    gsr_count  <<<NPTS/256, 256, 0, stream>>>(pos, ws);
    gsr_scan   <<<1, NCELL, 0, stream>>>(ws);
    gsr_scatter<<<NPTS/256, 256, 0, stream>>>(pos, rot, ws);
    gsr_qcell  <<<NCELL, 512, 0, stream>>>(scl, opa, ws, (float*)d_out);
}